// Round 16
// baseline (374.767 us; speedup 1.0000x reference)
//
#include <hip/hip_runtime.h>

// ModulatedConv2d: B=16, C=512->512, 3x3 SAME, per-sample demodulated weights.
// R12 = R10 byte-identical revert + T5 setprio around the MFMA cluster.
// R11 post-mortem: counted-vmcnt dbuf lost 3rd time (VGPR+AGPR=256 at the
// 2-wave cap -> no scheduler headroom; block desync broke A-slab L2 sharing
// [FETCH 94->185MB]; sched_barrier spam = m141). Lockstep drains are partly
// load-bearing (L2 temporal locality). R10 audit: phase-slot 7000cyc =
// 3725 MFMA + ~2300 LDS + ~1100 VALU + drain; all other catalog levers
// measured null/negative on this op. T5 is the last cheap untested lever:
// 2 independent block groups per CU = wave role diversity precondition.

typedef __bf16 bf16x8 __attribute__((ext_vector_type(8)));
typedef float f32x4 __attribute__((ext_vector_type(4)));

__device__ __forceinline__ void async16(const void* g, void* s) {
  __builtin_amdgcn_global_load_lds((const __attribute__((address_space(1))) void*)g,
                                   (__attribute__((address_space(3))) void*)s, 16, 0, 0);
}

// style[b][i] = dot(w_embs[b,:], style_W[i,:]) + style_b[i] + 1
__global__ __launch_bounds__(256) void k_style(const float* __restrict__ we,
                                               const float* __restrict__ sW,
                                               const float* __restrict__ sb,
                                               float* __restrict__ style) {
  int lane = threadIdx.x & 63, wid = threadIdx.x >> 6;
  int b = blockIdx.x >> 7;
  int i = ((blockIdx.x & 127) << 2) + wid;
  const float* wer = we + b * 512;
  const float* swr = sW + i * 512;
  float acc = 0.f;
  for (int d = lane; d < 512; d += 64) acc += wer[d] * swr[d];
#pragma unroll
  for (int off = 32; off; off >>= 1) acc += __shfl_xor(acc, off);
  if (lane == 0) style[b * 512 + i] = acc + sb[i] + 1.0f;
}

// wsq[o][i] = sum_k cw[o][i][k]^2
__global__ __launch_bounds__(256) void k_wsq(const float* __restrict__ cw,
                                             float* __restrict__ wsq) {
  int t = blockIdx.x * 256 + threadIdx.x;  // o*512+i
  const float* p = cw + (long)t * 9;
  float s = 0.f;
#pragma unroll
  for (int k = 0; k < 9; ++k) s += p[k] * p[k];
  wsq[t] = s;
}

// rnorm[b][o] = rsqrt(sum_i style[b,i]^2 * wsq[o,i])
__global__ __launch_bounds__(256) void k_rnorm(const float* __restrict__ style,
                                               const float* __restrict__ wsq,
                                               float* __restrict__ rnorm) {
  int lane = threadIdx.x & 63, wid = threadIdx.x >> 6;
  int idx = blockIdx.x * 4 + wid;  // b*512 + o
  int b = idx >> 9, o = idx & 511;
  float acc = 0.f;
  for (int i = lane; i < 512; i += 64) {
    float s = style[(b << 9) + i];
    acc += s * s * wsq[(o << 9) + i];
  }
#pragma unroll
  for (int off = 32; off; off >>= 1) acc += __shfl_xor(acc, off);
  if (lane == 0) rnorm[idx] = rsqrtf(acc);
}

// wt[b][t'][o][i], t' = kx*3 + ky (kx-MAJOR so a (ky=0..2,kx) slab is
// contiguous): value = cw[o][i][ky*3+kx] * style[b][i] * rnorm[b][o].
__global__ __launch_bounds__(256) void k_wt(const float* __restrict__ cw,
                                            const float* __restrict__ style,
                                            const float* __restrict__ rnorm,
                                            __bf16* __restrict__ wt) {
  int t = blockIdx.x * 256 + threadIdx.x;  // b*262144 + o*512 + i
  int b = t >> 18;
  int oi = t & 262143;
  int o = oi >> 9, i = oi & 511;
  float sc = style[(b << 9) + i] * rnorm[(b << 9) + o];
  const float* p = cw + (long)oi * 9;
#pragma unroll
  for (int k = 0; k < 9; ++k) {  // k = ky*3+kx  ->  t' = kx*3+ky
    int tp = (k % 3) * 3 + k / 3;
    wt[((long)(b * 9 + tp) << 18) + ((long)o << 9) + i] = (__bf16)(p[k] * sc);
  }
}

// xpad[b][r][c][i] (r,c in [0,66)) = bf16(imgs[b][i][r-1][c-1]), zero border.
__global__ __launch_bounds__(256) void k_xpad(const float* __restrict__ imgs,
                                              __bf16* __restrict__ xpad) {
  int t = blockIdx.x * 256 + threadIdx.x;  // b*4356 + r*66 + c
  if (t >= 16 * 4356) return;
  int b = t / 4356;
  int rc = t - b * 4356;
  int r = rc / 66, c = rc - (rc / 66) * 66;
  __bf16* dst = xpad + (long)t * 512;
  if (r == 0 || r == 65 || c == 0 || c == 65) {
    const f32x4 z = {0.f, 0.f, 0.f, 0.f};
#pragma unroll 4
    for (int j = 0; j < 64; ++j) *(f32x4*)(dst + j * 8) = z;
  } else {
    const float* src = imgs + ((long)b << 21) + ((r - 1) << 6) + (c - 1);
    for (int j = 0; j < 64; ++j) {
      bf16x8 v;
#pragma unroll
      for (int q = 0; q < 8; ++q) v[q] = (__bf16)src[(long)(j * 8 + q) << 12];
      *(bf16x8*)(dst + j * 8) = v;
    }
  }
}

// Conv: block = 128 o x 256 px (8h x 32w), 4 waves = 2(o) x 2(px), wave
// tile 64o x 128px, acc[4][8]. Phase = (icb64, hf, kx): stage 3-tap x 32ch
// A-slab (24.6KB) [+ X(340px,K=64) at first phase of icb]; compute
// bfr[6][2] once, sweep ky=0..2 with af[4] -> 96 MFMA/phase/wave.
// LDS: sX 45056 + sA3 24576 = 69632 B -> 2 blocks/CU.
__global__ __launch_bounds__(256, 2) void k_conv(const __bf16* __restrict__ xpad,
                                                 const __bf16* __restrict__ wt,
                                                 const float* __restrict__ bias,
                                                 float* __restrict__ out) {
  __shared__ __attribute__((aligned(16))) __bf16 sX[2816 * 8];      // 340 px used
  __shared__ __attribute__((aligned(16))) __bf16 sA3[3 * 128 * 32]; // 3-tap K=32

  const int tid = threadIdx.x;
  const int lane = tid & 63;
  const int wid = tid >> 6;
  const int wr = wid >> 1, wp = wid & 1;
  const int l15 = lane & 15, lq = lane >> 4;

  // T1 XCD-chunked swizzle (R10: FETCH 550->94MB). Grid 1024 = 8 x 128.
  const int bid0 = blockIdx.x;
  const int bid = ((bid0 & 7) << 7) | (bid0 >> 3);

  const int b = bid >> 6;          // 64 blocks / batch
  const int r6 = bid & 63;
  const int o0 = (r6 >> 4) << 7;   // 4 o-tiles of 128
  const int st = r6 & 15;          // 16 spatial tiles
  const int h0 = (st >> 1) << 3;   // 8 h-tiles * 8 rows
  const int w0 = (st & 1) << 5;    // 2 w-tiles * 32 cols
  const int b66 = b * 66;

  // X staging (R3-proven 340px geometry): slot s=it*256+tid (clamped 2719),
  // px p=s>>3, holds chunk j=(s&7)^(p&7); LDS pad slots 2720..2815 unused.
  const __bf16* xg[11];
#pragma unroll
  for (int it = 0; it < 11; ++it) {
    int s = it * 256 + tid;
    if (s > 2719) s = 2719;
    int p = s >> 3;
    int j = (s & 7) ^ (p & 7);
    int lr = p / 34, lc = p - (p / 34) * 34;
    xg[it] = xpad + ((long)((b66 + h0 + lr) * 66) + (w0 + lc)) * 512 + j * 8;
  }
  // A staging (R8-verbatim K=32 slab): it 0..5: tap=it>>1, rowgrp=it&1.
  const int abase = ((o0 + (tid >> 2)) << 9) + (((tid & 3) ^ ((tid >> 3) & 3)) << 3);
  const __bf16* wtb = wt + (long)b * 2359296;

  f32x4 acc[4][8];
  const f32x4 zero4 = {0.f, 0.f, 0.f, 0.f};
#pragma unroll
  for (int m = 0; m < 4; ++m)
#pragma unroll
    for (int n = 0; n < 8; ++n) acc[m][n] = zero4;

  const int arowbase = (wr << 6) + l15;          // A o-row for m=0
  const int csA = (lq ^ ((l15 >> 1) & 3)) << 3;  // A chunk swizzle (elems)
  const int rbase = wp << 2;                     // wave's first halo row

  bool first = true;
  for (int icb = 0; icb < 8; ++icb) {
    const int ic = icb << 6;
#pragma unroll
    for (int hf = 0; hf < 2; ++hf) {
#pragma unroll
      for (int kx = 0; kx < 3; ++kx) {
        if (!first) __syncthreads();  // prior compute done; safe to overwrite
        first = false;
        if (hf == 0 && kx == 0) {
#pragma unroll
          for (int it = 0; it < 11; ++it)
            async16(xg[it] + ic, (char*)sX + it * 4096 + (wid << 10));
        }
        {
          const __bf16* wa = wtb + abase + ic + (hf << 5);
#pragma unroll
          for (int it = 0; it < 6; ++it)
            async16(wa + (kx * 3 + (it >> 1)) * 262144 + (it & 1) * 32768,
                    (char*)sA3 + it * 4096 + (wid << 10));
        }
        __syncthreads();  // compiler drains vmcnt(0) before s_barrier
        // ---- compute: 96 MFMA from sA3 + sX (T5: prefer this wave) ----
        __builtin_amdgcn_s_setprio(1);
        const int jb = (hf << 2) | lq;  // sX chunk for this half
        bf16x8 bfr[6][2];
#pragma unroll
        for (int r = 0; r < 6; ++r)
#pragma unroll
          for (int c = 0; c < 2; ++c) {
            int p = (rbase + r) * 34 + (c << 4) + l15 + kx;
            bfr[r][c] = *(const bf16x8*)&sX[(p << 6) + ((jb ^ (p & 7)) << 3)];
          }
#pragma unroll
        for (int ky = 0; ky < 3; ++ky) {
          const __bf16* sAb = sA3 + ky * 4096;
          bf16x8 af[4];
#pragma unroll
          for (int m = 0; m < 4; ++m)
            af[m] = *(const bf16x8*)&sAb[((arowbase + (m << 4)) << 5) + csA];
#pragma unroll
          for (int m = 0; m < 4; ++m)
#pragma unroll
            for (int n = 0; n < 8; ++n)
              acc[m][n] = __builtin_amdgcn_mfma_f32_16x16x32_bf16(
                  af[m], bfr[(n >> 1) + ky][n & 1], acc[m][n], 0, 0, 0);
        }
        __builtin_amdgcn_s_setprio(0);
      }
    }
  }

  // Epilogue: C/D col=lane&15 (pixel), row=(lane>>4)*4+q (out chan).
  // pixel id = wp*128 + n*16 + l15 -> h = h0 + pid>>5, w = w0 + (pid&31).
  float* outb = out + ((long)b << 21);
#pragma unroll
  for (int m = 0; m < 4; ++m) {
    int ob = o0 + (wr << 6) + (m << 4) + (lq << 2);
#pragma unroll
    for (int n = 0; n < 8; ++n) {
      int pid = (wp << 7) + (n << 4) + l15;
      int h = h0 + (pid >> 5), w = w0 + (pid & 31);
#pragma unroll
      for (int q = 0; q < 4; ++q) {
        int o = ob + q;
        outb[((long)o << 12) + (h << 6) + w] = acc[m][n][q] + bias[o];
      }
    }
  }
}

extern "C" void kernel_launch(void* const* d_in, const int* in_sizes, int n_in,
                              void* d_out, int out_size, void* d_ws, size_t ws_size,
                              hipStream_t stream) {
  const float* imgs = (const float*)d_in[0];
  const float* w_embs = (const float*)d_in[1];
  const float* cw = (const float*)d_in[2];
  const float* bias = (const float*)d_in[3];
  const float* style_W = (const float*)d_in[4];
  const float* style_b = (const float*)d_in[5];
  float* out = (float*)d_out;

  char* ws = (char*)d_ws;
  float* style = (float*)(ws);                          // 32 KB
  float* rnorm = (float*)(ws + (32 << 10));             // 32 KB
  float* wsq = (float*)(ws + (64 << 10));               // 1 MB
  __bf16* wt = (__bf16*)(ws + (64 << 10) + (1 << 20));  // 75,497,472 B
  __bf16* xpad = (__bf16*)(ws + (64 << 10) + (1 << 20) + 75497472);  // 71,368,704 B
  size_t need = (size_t)(64 << 10) + (1 << 20) + 75497472ull + 71368704ull;
  if (ws_size < need) return;  // leaves d_out poisoned -> visible failure mode

  k_style<<<2048, 256, 0, stream>>>(w_embs, style_W, style_b, style);
  k_wsq<<<1024, 256, 0, stream>>>(cw, wsq);
  k_rnorm<<<2048, 256, 0, stream>>>(style, wsq, rnorm);
  k_wt<<<16384, 256, 0, stream>>>(cw, style, rnorm, wt);
  k_xpad<<<273, 256, 0, stream>>>(imgs, xpad);
  k_conv<<<1024, 256, 0, stream>>>(xpad, wt, bias, out);
}

// Round 17
// 331.018 us; speedup vs baseline: 1.1322x; 1.1322x over previous
//
#include <hip/hip_runtime.h>

// ModulatedConv2d: B=16, C=512->512, 3x3 SAME, per-sample demodulated weights.
// R16: k_conv = R12 VERBATIM (276us, converged: all catalog levers measured
// null/negative on this structure; residual = single-buffer stage-drain,
// escapable only by the full 8-phase template which failed 3x on this op).
// This round attacks the ~98us prepass (floor ~58us):
//  - k_xpad: 8x parallelism (grid 273->2178, 64 chans/thread) - was 4.3
//    waves/CU with 512 serial latency-bound loads per thread.
//  - k_wt: wave<->(b,o), lane<->i-octet; 72 contiguous f32 reads/thread,
//    9x bf16x8 stores (1KB/wave/inst vs 128B) - 8x store efficiency.

typedef __bf16 bf16x8 __attribute__((ext_vector_type(8)));
typedef float f32x4 __attribute__((ext_vector_type(4)));

__device__ __forceinline__ void async16(const void* g, void* s) {
  __builtin_amdgcn_global_load_lds((const __attribute__((address_space(1))) void*)g,
                                   (__attribute__((address_space(3))) void*)s, 16, 0, 0);
}

// style[b][i] = dot(w_embs[b,:], style_W[i,:]) + style_b[i] + 1
__global__ __launch_bounds__(256) void k_style(const float* __restrict__ we,
                                               const float* __restrict__ sW,
                                               const float* __restrict__ sb,
                                               float* __restrict__ style) {
  int lane = threadIdx.x & 63, wid = threadIdx.x >> 6;
  int b = blockIdx.x >> 7;
  int i = ((blockIdx.x & 127) << 2) + wid;
  const float* wer = we + b * 512;
  const float* swr = sW + i * 512;
  float acc = 0.f;
  for (int d = lane; d < 512; d += 64) acc += wer[d] * swr[d];
#pragma unroll
  for (int off = 32; off; off >>= 1) acc += __shfl_xor(acc, off);
  if (lane == 0) style[b * 512 + i] = acc + sb[i] + 1.0f;
}

// wsq[o][i] = sum_k cw[o][i][k]^2
__global__ __launch_bounds__(256) void k_wsq(const float* __restrict__ cw,
                                             float* __restrict__ wsq) {
  int t = blockIdx.x * 256 + threadIdx.x;  // o*512+i
  const float* p = cw + (long)t * 9;
  float s = 0.f;
#pragma unroll
  for (int k = 0; k < 9; ++k) s += p[k] * p[k];
  wsq[t] = s;
}

// rnorm[b][o] = rsqrt(sum_i style[b,i]^2 * wsq[o,i])
__global__ __launch_bounds__(256) void k_rnorm(const float* __restrict__ style,
                                               const float* __restrict__ wsq,
                                               float* __restrict__ rnorm) {
  int lane = threadIdx.x & 63, wid = threadIdx.x >> 6;
  int idx = blockIdx.x * 4 + wid;  // b*512 + o
  int b = idx >> 9, o = idx & 511;
  float acc = 0.f;
  for (int i = lane; i < 512; i += 64) {
    float s = style[(b << 9) + i];
    acc += s * s * wsq[(o << 9) + i];
  }
#pragma unroll
  for (int off = 32; off; off >>= 1) acc += __shfl_xor(acc, off);
  if (lane == 0) rnorm[idx] = rsqrtf(acc);
}

// wt[b][t'][o][i], t' = kx*3 + ky (kx-MAJOR). Wave <-> (b,o), lane <-> i-octet:
// reads cw[o][i0..i0+7][0..8] = 72 contiguous f32/thread (wave covers o's
// full 18.4KB row), stores one bf16x8 per tap (1KB/wave/inst, coalesced).
__global__ __launch_bounds__(256) void k_wt(const float* __restrict__ cw,
                                            const float* __restrict__ style,
                                            const float* __restrict__ rnorm,
                                            __bf16* __restrict__ wt) {
  int t = blockIdx.x * 256 + threadIdx.x;  // 524,288 threads
  int ib = t & 63;             // lane = i-octet
  int w = t >> 6;              // wave = (b,o)
  int o = w & 511, b = w >> 9;
  int i0 = ib << 3;
  float rn = rnorm[(b << 9) + o];
  const float* cwo = cw + (long)o * 4608 + (long)i0 * 9;
  const float* stb = style + (b << 9) + i0;
  float st[8];
#pragma unroll
  for (int q = 0; q < 8; ++q) st[q] = stb[q] * rn;
#pragma unroll
  for (int k = 0; k < 9; ++k) {  // k = ky*3+kx -> t' = kx*3+ky
    int tp = (k % 3) * 3 + k / 3;
    bf16x8 v;
#pragma unroll
    for (int q = 0; q < 8; ++q) v[q] = (__bf16)(cwo[q * 9 + k] * st[q]);
    *(bf16x8*)(wt + ((long)(b * 9 + tp) << 18) + ((long)o << 9) + i0) = v;
  }
}

// xpad[b][r][c][i] (r,c in [0,66)) = bf16(imgs[b][i][r-1][c-1]), zero border.
// Thread <-> (chan-block of 64, pixel): 8x more parallelism than per-pixel
// (557,568 threads, 34 waves/CU), 8 f32 coalesced loads per j-octet, 128B
// contiguous stores per thread. 69696 = 64*1089 -> waves never straddle cb.
__global__ __launch_bounds__(256) void k_xpad(const float* __restrict__ imgs,
                                              __bf16* __restrict__ xpad) {
  int t = blockIdx.x * 256 + threadIdx.x;  // 2178*256 = 557,568 exact
  int px = t % 69696;
  int cb = t / 69696;
  int b = px / 4356;
  int rc = px - b * 4356;
  int r = rc / 66, c = rc - (rc / 66) * 66;
  __bf16* dst = xpad + (long)px * 512 + (cb << 6);
  if (r == 0 || r == 65 || c == 0 || c == 65) {
    const f32x4 z = {0.f, 0.f, 0.f, 0.f};
#pragma unroll
    for (int j = 0; j < 8; ++j) *(f32x4*)(dst + j * 8) = z;
  } else {
    const float* src = imgs + ((long)b << 21) + ((r - 1) << 6) + (c - 1) +
                       ((long)(cb << 6) << 12);
#pragma unroll
    for (int j = 0; j < 8; ++j) {
      bf16x8 v;
#pragma unroll
      for (int q = 0; q < 8; ++q) v[q] = (__bf16)src[(long)(j * 8 + q) << 12];
      *(bf16x8*)(dst + j * 8) = v;
    }
  }
}

// Conv (R12 verbatim): block = 128 o x 256 px (8h x 32w), 4 waves 2(o)x2(px),
// wave tile 64o x 128px, acc[4][8]. Phase = (icb64, hf, kx): stage 3-tap x
// 32ch A-slab [+ X at first phase of icb]; bfr[6][2] once, sweep ky with
// af[4] -> 96 MFMA/phase/wave. LDS 69632 -> 2 blocks/CU. T1 XCD swizzle,
// T2 chunk swizzles, T5 setprio.
__global__ __launch_bounds__(256, 2) void k_conv(const __bf16* __restrict__ xpad,
                                                 const __bf16* __restrict__ wt,
                                                 const float* __restrict__ bias,
                                                 float* __restrict__ out) {
  __shared__ __attribute__((aligned(16))) __bf16 sX[2816 * 8];      // 340 px used
  __shared__ __attribute__((aligned(16))) __bf16 sA3[3 * 128 * 32]; // 3-tap K=32

  const int tid = threadIdx.x;
  const int lane = tid & 63;
  const int wid = tid >> 6;
  const int wr = wid >> 1, wp = wid & 1;
  const int l15 = lane & 15, lq = lane >> 4;

  const int bid0 = blockIdx.x;
  const int bid = ((bid0 & 7) << 7) | (bid0 >> 3);

  const int b = bid >> 6;          // 64 blocks / batch
  const int r6 = bid & 63;
  const int o0 = (r6 >> 4) << 7;   // 4 o-tiles of 128
  const int st = r6 & 15;          // 16 spatial tiles
  const int h0 = (st >> 1) << 3;   // 8 h-tiles * 8 rows
  const int w0 = (st & 1) << 5;    // 2 w-tiles * 32 cols
  const int b66 = b * 66;

  const __bf16* xg[11];
#pragma unroll
  for (int it = 0; it < 11; ++it) {
    int s = it * 256 + tid;
    if (s > 2719) s = 2719;
    int p = s >> 3;
    int j = (s & 7) ^ (p & 7);
    int lr = p / 34, lc = p - (p / 34) * 34;
    xg[it] = xpad + ((long)((b66 + h0 + lr) * 66) + (w0 + lc)) * 512 + j * 8;
  }
  const int abase = ((o0 + (tid >> 2)) << 9) + (((tid & 3) ^ ((tid >> 3) & 3)) << 3);
  const __bf16* wtb = wt + (long)b * 2359296;

  f32x4 acc[4][8];
  const f32x4 zero4 = {0.f, 0.f, 0.f, 0.f};
#pragma unroll
  for (int m = 0; m < 4; ++m)
#pragma unroll
    for (int n = 0; n < 8; ++n) acc[m][n] = zero4;

  const int arowbase = (wr << 6) + l15;          // A o-row for m=0
  const int csA = (lq ^ ((l15 >> 1) & 3)) << 3;  // A chunk swizzle (elems)
  const int rbase = wp << 2;                     // wave's first halo row

  bool first = true;
  for (int icb = 0; icb < 8; ++icb) {
    const int ic = icb << 6;
#pragma unroll
    for (int hf = 0; hf < 2; ++hf) {
#pragma unroll
      for (int kx = 0; kx < 3; ++kx) {
        if (!first) __syncthreads();  // prior compute done; safe to overwrite
        first = false;
        if (hf == 0 && kx == 0) {
#pragma unroll
          for (int it = 0; it < 11; ++it)
            async16(xg[it] + ic, (char*)sX + it * 4096 + (wid << 10));
        }
        {
          const __bf16* wa = wtb + abase + ic + (hf << 5);
#pragma unroll
          for (int it = 0; it < 6; ++it)
            async16(wa + (kx * 3 + (it >> 1)) * 262144 + (it & 1) * 32768,
                    (char*)sA3 + it * 4096 + (wid << 10));
        }
        __syncthreads();  // compiler drains vmcnt(0) before s_barrier
        // ---- compute: 96 MFMA from sA3 + sX (T5) ----
        __builtin_amdgcn_s_setprio(1);
        const int jb = (hf << 2) | lq;  // sX chunk for this half
        bf16x8 bfr[6][2];
#pragma unroll
        for (int r = 0; r < 6; ++r)
#pragma unroll
          for (int c = 0; c < 2; ++c) {
            int p = (rbase + r) * 34 + (c << 4) + l15 + kx;
            bfr[r][c] = *(const bf16x8*)&sX[(p << 6) + ((jb ^ (p & 7)) << 3)];
          }
#pragma unroll
        for (int ky = 0; ky < 3; ++ky) {
          const __bf16* sAb = sA3 + ky * 4096;
          bf16x8 af[4];
#pragma unroll
          for (int m = 0; m < 4; ++m)
            af[m] = *(const bf16x8*)&sAb[((arowbase + (m << 4)) << 5) + csA];
#pragma unroll
          for (int m = 0; m < 4; ++m)
#pragma unroll
            for (int n = 0; n < 8; ++n)
              acc[m][n] = __builtin_amdgcn_mfma_f32_16x16x32_bf16(
                  af[m], bfr[(n >> 1) + ky][n & 1], acc[m][n], 0, 0, 0);
        }
        __builtin_amdgcn_s_setprio(0);
      }
    }
  }

  // Epilogue: C/D col=lane&15 (pixel), row=(lane>>4)*4+q (out chan).
  float* outb = out + ((long)b << 21);
#pragma unroll
  for (int m = 0; m < 4; ++m) {
    int ob = o0 + (wr << 6) + (m << 4) + (lq << 2);
#pragma unroll
    for (int n = 0; n < 8; ++n) {
      int pid = (wp << 7) + (n << 4) + l15;
      int h = h0 + (pid >> 5), w = w0 + (pid & 31);
#pragma unroll
      for (int q = 0; q < 4; ++q) {
        int o = ob + q;
        outb[((long)o << 12) + (h << 6) + w] = acc[m][n][q] + bias[o];
      }
    }
  }
}

extern "C" void kernel_launch(void* const* d_in, const int* in_sizes, int n_in,
                              void* d_out, int out_size, void* d_ws, size_t ws_size,
                              hipStream_t stream) {
  const float* imgs = (const float*)d_in[0];
  const float* w_embs = (const float*)d_in[1];
  const float* cw = (const float*)d_in[2];
  const float* bias = (const float*)d_in[3];
  const float* style_W = (const float*)d_in[4];
  const float* style_b = (const float*)d_in[5];
  float* out = (float*)d_out;

  char* ws = (char*)d_ws;
  float* style = (float*)(ws);                          // 32 KB
  float* rnorm = (float*)(ws + (32 << 10));             // 32 KB
  float* wsq = (float*)(ws + (64 << 10));               // 1 MB
  __bf16* wt = (__bf16*)(ws + (64 << 10) + (1 << 20));  // 75,497,472 B
  __bf16* xpad = (__bf16*)(ws + (64 << 10) + (1 << 20) + 75497472);  // 71,368,704 B
  size_t need = (size_t)(64 << 10) + (1 << 20) + 75497472ull + 71368704ull;
  if (ws_size < need) return;  // leaves d_out poisoned -> visible failure mode

  k_style<<<2048, 256, 0, stream>>>(w_embs, style_W, style_b, style);
  k_wsq<<<1024, 256, 0, stream>>>(cw, wsq);
  k_rnorm<<<2048, 256, 0, stream>>>(style, wsq, rnorm);
  k_wt<<<2048, 256, 0, stream>>>(cw, style, rnorm, wt);
  k_xpad<<<2178, 256, 0, stream>>>(imgs, xpad);
  k_conv<<<1024, 256, 0, stream>>>(xpad, wt, bias, out);
}